// Round 10
// baseline (74.360 us; speedup 1.0000x reference)
//
#include <hip/hip_runtime.h>
#include <hip/hip_bf16.h>

// MoE gate (DeepSeek-V2 style): logits = X @ W^T, softmax, group-limited
// top-3-of-8 groups, top-6 experts, normalized weights (sorted desc).
//
// X: [T=32768, H=2048] fp32   W: [64, 2048] fp32   out: [T, 6] fp32
//
// Precision (r9, verified): fp32 = hi+lo FP16 (22 mantissa bits, residual
// split exact, dropped lo*lo ~2^-22). 3 MFMA passes (hh, hl, lh).
//
// Round-10 change vs r9 (72us): TLP DECOUPLING only (r7's idea minus its
// confounds). 256-thr blocks (4 waves), 64 tokens/block, 512 blocks ->
// 2 INDEPENDENT blocks/CU (2 x 64KB LDS = 128 <= 160KB). Same waves/CU as
// r9 but two barrier domains: block 0's chunk-boundary drain overlaps
// block 1's compute. Ring stays 4-deep, chunks stay K-128, staging becomes
// 4 units/wave/chunk. launch_bounds (256,2) -> VGPR cap 256, no spill.

#define HD 2048
#define NE 64
#define NCH 16       // K-chunks of 128
#define BUFB 32768   // bytes per LDS B buffer: 4 steps * 2 splits * 4KB

typedef __attribute__((ext_vector_type(4))) float f4;
typedef __attribute__((ext_vector_type(8))) short s8;
typedef __attribute__((ext_vector_type(8))) _Float16 h8;
typedef __attribute__((ext_vector_type(4))) float accv;
typedef unsigned short u16;

// fp32 -> hi/lo fp16 split (RNE; residual exact; dropped term ~2^-22).
__device__ __forceinline__ void split8h(const f4 v0, const f4 v1, s8& h, s8& l) {
  #pragma unroll
  for (int i = 0; i < 8; ++i) {
    float a = (i < 4) ? v0[i] : v1[i - 4];
    _Float16 hh = (_Float16)a;
    float r = a - (float)hh;
    _Float16 ll = (_Float16)r;
    h[i] = __builtin_bit_cast(short, hh);
    l[i] = __builtin_bit_cast(short, ll);
  }
}

__device__ __forceinline__ accv mfma3(s8 ah, s8 al, s8 bh, s8 bl, accv t) {
  h8 AH = __builtin_bit_cast(h8, ah);
  h8 AL = __builtin_bit_cast(h8, al);
  h8 BH = __builtin_bit_cast(h8, bh);
  h8 BL = __builtin_bit_cast(h8, bl);
  t = __builtin_amdgcn_mfma_f32_16x16x32_f16(AH, BH, t, 0, 0, 0);
  t = __builtin_amdgcn_mfma_f32_16x16x32_f16(AH, BL, t, 0, 0, 0);
  t = __builtin_amdgcn_mfma_f32_16x16x32_f16(AL, BH, t, 0, 0, 0);
  return t;
}

// Shared epilogue: v[64] logits -> top-3 groups -> top-6 -> normalized weights.
__device__ __forceinline__ void epilogue64(const float* v, float* op) {
  float gm[8];
  #pragma unroll
  for (int g = 0; g < 8; ++g) {
    float mx = v[g * 8];
    #pragma unroll
    for (int j = 1; j < 8; ++j) mx = fmaxf(mx, v[g * 8 + j]);
    gm[g] = mx;
  }
  unsigned selmask = 0u;
  #pragma unroll
  for (int itg = 0; itg < 3; ++itg) {
    float best = gm[0];
    #pragma unroll
    for (int g = 1; g < 8; ++g) best = fmaxf(best, gm[g]);
    int bi = 7;
    #pragma unroll
    for (int g = 6; g >= 0; --g)
      if (gm[g] == best) bi = g;
    selmask |= (1u << bi);
    #pragma unroll
    for (int g = 0; g < 8; ++g) gm[g] = (g == bi) ? -3.0e38f : gm[g];
  }
  float t0 = -3.0e38f, t1 = -3.0e38f, t2 = -3.0e38f;
  float t3 = -3.0e38f, t4 = -3.0e38f, t5 = -3.0e38f;
  #pragma unroll
  for (int g = 0; g < 8; ++g) {
    const bool sel = (selmask >> g) & 1u;
    #pragma unroll
    for (int j = 0; j < 8; ++j) {
      float x = sel ? v[g * 8 + j] : -3.0e38f;
      float mm;
      mm = fmaxf(t0, x); x = fminf(t0, x); t0 = mm;
      mm = fmaxf(t1, x); x = fminf(t1, x); t1 = mm;
      mm = fmaxf(t2, x); x = fminf(t2, x); t2 = mm;
      mm = fmaxf(t3, x); x = fminf(t3, x); t3 = mm;
      mm = fmaxf(t4, x); x = fminf(t4, x); t4 = mm;
      t5 = fmaxf(t5, x);
    }
  }
  float e0 = 1.0f;
  float e1 = __expf(t1 - t0);
  float e2 = __expf(t2 - t0);
  float e3 = __expf(t3 - t0);
  float e4 = __expf(t4 - t0);
  float e5 = __expf(t5 - t0);
  float sum = e0 + e1 + e2 + e3 + e4 + e5;
  float inv = 1.0f / sum;
  op[0] = e0 * inv; op[1] = e1 * inv; op[2] = e2 * inv;
  op[3] = e3 * inv; op[4] = e4 * inv; op[5] = e5 * inv;
}

// ---- kernel 1: split gate weights fp32 -> {hi,lo} fp16 in d_ws ------------
__global__ __launch_bounds__(256) void cvtW2(const float* __restrict__ Wf,
                                             u16* __restrict__ Wh,
                                             u16* __restrict__ Wl) {
  int i = (blockIdx.x * 256 + threadIdx.x) * 8;  // 64 blocks cover 131072
  f4 v0 = *(const f4*)(Wf + i);
  f4 v1 = *(const f4*)(Wf + i + 4);
  s8 h, l;
  split8h(v0, v1, h, l);
  *(s8*)((short*)Wh + i) = h;
  *(s8*)((short*)Wl + i) = l;
}

// ---- kernel 2: fused gate (fp16 2-split, 4-wave blocks, 2 blocks/CU) -------
template <bool PRE>
__global__ __launch_bounds__(256, 2) void gateF(
    const float* __restrict__ X, const float* __restrict__ Wf,
    const u16* __restrict__ Wh, const u16* __restrict__ Wl,
    float* __restrict__ out) {
  __shared__ __align__(16) unsigned char smem[2 * BUFB];  // 64 KB

  const int tid = threadIdx.x;
  const int lane = tid & 63;
  const int w = tid >> 6;      // wave 0..3 -> owns tokens tok0 + w*16 ..
  const int ec = lane & 15;    // token row (A) / expert col (B)
  const int kg = lane >> 4;    // 0..3 (8 consecutive k)
  const int tok0 = blockIdx.x * 64;

  // A stream: this wave's 16 token rows
  const float* pA = X + (size_t)(tok0 + w * 16 + ec) * HD + kg * 8;

  // staging roles: wave w stages step sh=w, all 4 expert-groups sg=0..3.
  // wsrc(sg) = (sg*16+ec)*HD + w*32 + kg*8 ; dst = ((w*2+split)*4+sg)*1024
  const size_t wsrcb = (size_t)ec * HD + w * 32 + kg * 8;
  const int sdstb = w * 8 * 1024 + lane * 16;  // + sg*1024, + split*4096

  accv acc[4];
  #pragma unroll
  for (int f = 0; f < 4; ++f) acc[f] = (accv){0.f, 0.f, 0.f, 0.f};

  f4 ar[4][2];  // A raw ring, 4-step lookahead (static slots)

  // --- prologue: stage chunk 0 into buf0; prefetch A steps 0..3 ---
  {
    #pragma unroll
    for (int g = 0; g < 4; ++g) {
      const size_t o = wsrcb + (size_t)g * 16 * HD;
      s8 th, tl;
      if constexpr (PRE) {
        th = *(const s8*)(Wh + o);
        tl = *(const s8*)(Wl + o);
      } else {
        f4 r0 = *(const f4*)(Wf + o);
        f4 r1 = *(const f4*)(Wf + o + 4);
        split8h(r0, r1, th, tl);
      }
      unsigned char* d = smem + sdstb + g * 1024;
      *(s8*)(d) = th;
      *(s8*)(d + 4096) = tl;
    }
  }
  #pragma unroll
  for (int st = 0; st < 4; ++st) {
    ar[st][0] = *(const f4*)(pA + st * 32);
    ar[st][1] = *(const f4*)(pA + st * 32 + 4);
  }
  asm volatile("s_waitcnt lgkmcnt(0)");
  __builtin_amdgcn_s_barrier();
  __builtin_amdgcn_sched_barrier(0);

  // --- main loop: 16 chunks of K=128 (4 MFMA-steps each) ---
  for (int c = 0; c < NCH; ++c) {
    const unsigned char* rb = smem + (c & 1) * BUFB;
    unsigned char* wb = smem + ((c + 1) & 1) * BUFB;
    const bool do_stage = (c + 1 < NCH);

    // issue next-chunk B loads NOW (written to LDS after compute: T14 split)
    s8 th[4], tl[4];
    f4 q0[4], q1[4];
    if (do_stage) {
      #pragma unroll
      for (int g = 0; g < 4; ++g) {
        const size_t o = wsrcb + (size_t)g * 16 * HD + (size_t)(c + 1) * 128;
        if constexpr (PRE) {
          th[g] = *(const s8*)(Wh + o);
          tl[g] = *(const s8*)(Wl + o);
        } else {
          q0[g] = *(const f4*)(Wf + o);
          q1[g] = *(const f4*)(Wf + o + 4);
        }
      }
    }

    #pragma unroll
    for (int st = 0; st < 4; ++st) {
      const int t = c * 4 + st;
      s8 ah, al;
      split8h(ar[st][0], ar[st][1], ah, al);
      const int tn = (t + 4 < 64) ? (t + 4) : 63;  // clamp; dup load harmless
      ar[st][0] = *(const f4*)(pA + tn * 32);
      ar[st][1] = *(const f4*)(pA + tn * 32 + 4);
      #pragma unroll
      for (int f = 0; f < 4; ++f) {
        const unsigned char* bp = rb + st * 8192 + f * 1024 + lane * 16;
        s8 bh = *(const s8*)(bp);
        s8 bl = *(const s8*)(bp + 4096);
        acc[f] = mfma3(ah, al, bh, bl, acc[f]);
      }
    }

    // write staged B (loads have had 4 steps to land)
    if (do_stage) {
      #pragma unroll
      for (int g = 0; g < 4; ++g) {
        if constexpr (!PRE) split8h(q0[g], q1[g], th[g], tl[g]);
        unsigned char* d = wb + sdstb + g * 1024;
        *(s8*)(d) = th[g];
        *(s8*)(d + 4096) = tl[g];
      }
    }
    // boundary: LDS-only drain; A vmcnt stream NEVER drained
    __builtin_amdgcn_sched_barrier(0);
    asm volatile("s_waitcnt lgkmcnt(0)");
    __builtin_amdgcn_s_barrier();
    __builtin_amdgcn_sched_barrier(0);
  }

  // --- epilogue: per-wave logit scatter (own region, no barrier needed) ---
  float* lf = (float*)smem + w * 1088;  // 16 tok x 68 floats
  #pragma unroll
  for (int f = 0; f < 4; ++f)
    #pragma unroll
    for (int r = 0; r < 4; ++r)
      lf[(kg * 4 + r) * 68 + f * 16 + ec] = acc[f][r];

  if (lane < 16) {
    float v[64];
    #pragma unroll
    for (int i = 0; i < 16; ++i) {
      f4 q = *(const f4*)(lf + lane * 68 + 4 * i);
      v[4 * i + 0] = q.x; v[4 * i + 1] = q.y;
      v[4 * i + 2] = q.z; v[4 * i + 3] = q.w;
    }
    epilogue64(v, out + (size_t)(tok0 + w * 16 + lane) * 6);
  }
}

extern "C" void kernel_launch(void* const* d_in, const int* in_sizes, int n_in,
                              void* d_out, int out_size, void* d_ws, size_t ws_size,
                              hipStream_t stream) {
  const float* X = (const float*)d_in[0];
  const float* Wf = (const float*)d_in[1];
  float* out = (float*)d_out;
  const int T = in_sizes[0] / HD;  // 32768
  const int nblk = T / 64;         // 512 blocks of 256 threads (4 waves)

  const size_t need = (size_t)NE * HD * sizeof(u16);  // 256 KB per split
  if (ws_size >= 2 * need) {
    u16* Whi = (u16*)d_ws;
    u16* Wlo = Whi + (size_t)NE * HD;
    cvtW2<<<dim3(64), dim3(256), 0, stream>>>(Wf, Whi, Wlo);
    gateF<true><<<dim3(nblk), dim3(256), 0, stream>>>(X, Wf, Whi, Wlo, out);
  } else {
    gateF<false><<<dim3(nblk), dim3(256), 0, stream>>>(X, Wf, nullptr, nullptr, out);
  }
}